// Round 12
// baseline (342.768 us; speedup 1.0000x reference)
//
#include <hip/hip_runtime.h>

#define SEQ    2048
#define HD     128
#define BN     64
#define NITER  (SEQ / BN)
#define NKVH   16
#define TILE_E 8192   // f16 elements per 64x128 tile (16 KB)

typedef __fp16 f16x4  __attribute__((ext_vector_type(4)));
typedef __fp16 f16x8  __attribute__((ext_vector_type(8)));
typedef float  f32x4  __attribute__((ext_vector_type(4)));
typedef float  f32x16 __attribute__((ext_vector_type(16)));

// pack two fp32 -> one uint of two f16 (RTZ)
__device__ __forceinline__ unsigned pkh(float a, float b) {
  auto h = __builtin_amdgcn_cvt_pkrtz(a, b);
  return __builtin_bit_cast(unsigned, h);
}

// direct HBM/L2 -> LDS DMA, 16 B per lane; lds dest wave-uniform base + lane*16
__device__ __forceinline__ void gl_lds16(const unsigned short* g, unsigned short* l) {
  __builtin_amdgcn_global_load_lds(
      (const __attribute__((address_space(1))) void*)g,
      (__attribute__((address_space(3))) void*)l, 16, 0, 0);
}

// ---------------------------------------------------------------------------
// Pass 1: K,V fp32 -> f16 in workspace.
// K: 64x128 tiles pre-swizzled in the main kernel's LDS byte layout
//    (16B chunk j at pos j ^ (row&15)) -- staged via LDS, dumped linearly.
// V: paired-frag FRAGMENT-MAJOR LINEAR (no LDS, no swizzle): 16B unit
//    u(c8,d) at int4 index T*1024 + c8*128 + d, where unit c8 = 2t+hi holds
//    [frag(g=2t,hi) | frag(g=2t+1,hi)], frag(g,hi) = f16 V^T[d][k=8g+4hi..+3]
//    (R11-verified pairing; reader does ONE dwordx4 per (t,dt)).
// ---------------------------------------------------------------------------
__global__ __launch_bounds__(256)
void cvt_kv(const float* __restrict__ K, const float* __restrict__ V,
            unsigned short* __restrict__ Kw, unsigned short* __restrict__ Vw)
{
  __shared__ unsigned short kt[TILE_E];
  const int tid = threadIdx.x;
  const int T   = blockIdx.x;               // 0..511 = hh*32 + t
  const long base = (long)T * TILE_E;       // fp32 element offset (same count)

  // K staging (R0-verified arithmetic)
  const int krow = tid >> 2, kq4 = tid & 3;
  const float* kp = K + base + (long)krow * HD + kq4 * 32;
#pragma unroll
  for (int jj = 0; jj < 4; ++jj) {
    float4 e = ((const float4*)kp)[2 * jj];
    float4 o = ((const float4*)kp)[2 * jj + 1];
    int4 ksj;
    ksj.x = (int)pkh(e.x, e.y);
    ksj.y = (int)pkh(e.z, e.w);
    ksj.z = (int)pkh(o.x, o.y);
    ksj.w = (int)pkh(o.z, o.w);
    int j = kq4 * 4 + jj;
    int pos = j ^ (krow & 15);
    *(int4*)(kt + krow * HD + pos * 8) = ksj;
  }

  // V paired-frag direct stores: thread (kq, dc8) owns frag k=4kq..4kq+3
  // for 8 d's.  g = kq>>1, hi = kq&1; unit c8 = 2*(kq>>2)+(kq&1);
  // half-within-unit = (kq>>1)&1.
  const int kq = tid >> 4, dc8 = tid & 15;
  const float* vp = V + base + (long)(4 * kq) * HD + dc8 * 8;
  float4 vr[4][2];
#pragma unroll
  for (int r = 0; r < 4; ++r) {
    vr[r][0] = ((const float4*)(vp + r * HD))[0];
    vr[r][1] = ((const float4*)(vp + r * HD))[1];
  }
  const int c8u  = 2 * (kq >> 2) + (kq & 1);
  const int half = (kq >> 1) & 1;
  uint2* vw2 = (uint2*)Vw;
#pragma unroll
  for (int jd = 0; jd < 8; ++jd) {
    const int hsel = jd >> 2, e = jd & 3;
    uint2 v2;
    v2.x = pkh(((const float*)&vr[0][hsel])[e], ((const float*)&vr[1][hsel])[e]);
    v2.y = pkh(((const float*)&vr[2][hsel])[e], ((const float*)&vr[3][hsel])[e]);
    int d = dc8 * 8 + jd;
    vw2[((long)T * 1024 + c8u * 128 + d) * 2 + half] = v2;
  }

  __syncthreads();
  // linear dump K LDS -> workspace (coalesced dwordx4)
  int4* kd = (int4*)(Kw + (long)T * TILE_E);
  const int4* ksrc = (const int4*)kt;
#pragma unroll
  for (int i = 0; i < 4; ++i)
    kd[i * 256 + tid] = ksrc[i * 256 + tid];
}

// ---------------------------------------------------------------------------
// Pass 2: attention.
//  - K: global_load_lds DMA of pre-swizzled tiles, LDS double-buffered,
//    one barrier/iter, zero staging registers, zero bank conflicts.
//  - V: NEVER in LDS. PV reads paired-frag dwordx4 units straight from the
//    workspace (L1/L2-resident; identical addresses across all 8 waves/CU).
//    Prefetch: t=0,1 issued BEFORE softmax (~500cy cover); t+2 issued at t.
//    -> LDS read traffic halves; V rides the TA/L1 pipe in parallel.
//  - PV: 32x32x8 MFMA, lane-local P (R9/R11-verified mapping, no shuffles).
// ---------------------------------------------------------------------------
__global__ __launch_bounds__(256, 2)
void fa_gqa_kernel(const float* __restrict__ Q,
                   const unsigned short* __restrict__ Kw,
                   const unsigned short* __restrict__ Vw,
                   float* __restrict__ O)
{
  __shared__ unsigned short kt_lds[2][TILE_E];   // 32 KB total

  const int tid  = threadIdx.x;
  const int lane = tid & 63;
  const int w    = tid >> 6;
  const int ml   = lane & 31;   // 32x32 MFMA row/col lane index
  const int hi   = lane >> 5;   // half-wave select

  // XCD-clustered virtual block mapping (K/V L2 locality)
  const int F     = blockIdx.x;        // 0..1023
  const int xcd   = F & 7;
  const int s     = F >> 3;
  const int bh    = xcd * 8 + (s >> 4);
  const int qtile = s & 15;

  const int b = bh >> 5;
  const int h = bh & 31;
  const long qrow0 = (long)bh * SEQ + qtile * 128 + w * 32;
  const float* Qw = Q + qrow0 * HD;
  float*       Ow = O + qrow0 * HD;
  const int kvh = b * 8 + (h >> 2);

  // Q fragments (B-operand of 32x32x16: lane holds Q[q=w*32+ml][d=dc*16+hi*8+j])
  f16x8 qf[8];
#pragma unroll
  for (int dc = 0; dc < 8; ++dc) {
    const float4* qp = (const float4*)(Qw + ml * HD + dc * 16 + hi * 8);
    float4 a = qp[0], bq = qp[1];
    int4 t;
    t.x = (int)pkh(a.x, a.y);
    t.y = (int)pkh(a.z, a.w);
    t.z = (int)pkh(bq.x, bq.y);
    t.w = (int)pkh(bq.z, bq.w);
    qf[dc] = __builtin_bit_cast(f16x8, t);
  }

  // O^T accumulators: 4 d-tiles of 32x32; lane holds O[q=ml][d=dt*32+(r&3)+8(r>>2)+4hi]
  f32x16 oacc[4];
#pragma unroll
  for (int dt = 0; dt < 4; ++dt)
    oacc[dt] = (f32x16)(0.f);

  float mst = -1e30f;
  float lst = 0.f;

  const float K1 = 0.08838834764831845f * 1.4426950408889634f; // scale*log2(e)

  // K staging: wave w copies quarter w (4 KB); pre-swizzled source, linear dest
  const unsigned short* kwb = Kw + (long)kvh * NITER * TILE_E;
  const int woff = w * 2048;  // elements = 4 KB

  // V paired-frag units: (2t+hi)*128 + dt*32+ml, int4-indexed
  const int4* vw4 = (const int4*)Vw + (long)kvh * NITER * 1024;
  const int vbase = hi * 128 + ml;

  // prologue: issue K tile 0 into buf 0
  {
    const unsigned short* ks = kwb + woff + lane * 8;
#pragma unroll
    for (int c = 0; c < 4; ++c)
      gl_lds16(ks + c * 512, &kt_lds[0][woff + c * 512]);
  }

// one PV step: two 32x32x8 MFMAs per dt from one prefetched int4 unit
#define PVSTEP(T_, VB_)                                                        \
  do {                                                                         \
    const int g0_ = 2 * (T_), g1_ = g0_ + 1;                                   \
    unsigned a0_ = pkh(sacc[g0_ >> 2][4 * (g0_ & 3) + 0],                      \
                       sacc[g0_ >> 2][4 * (g0_ & 3) + 1]);                     \
    unsigned a1_ = pkh(sacc[g0_ >> 2][4 * (g0_ & 3) + 2],                      \
                       sacc[g0_ >> 2][4 * (g0_ & 3) + 3]);                     \
    unsigned b0_ = pkh(sacc[g1_ >> 2][4 * (g1_ & 3) + 0],                      \
                       sacc[g1_ >> 2][4 * (g1_ & 3) + 1]);                     \
    unsigned b1_ = pkh(sacc[g1_ >> 2][4 * (g1_ & 3) + 2],                      \
                       sacc[g1_ >> 2][4 * (g1_ & 3) + 3]);                     \
    int2 p0i_; p0i_.x = (int)a0_; p0i_.y = (int)a1_;                           \
    int2 p1i_; p1i_.x = (int)b0_; p1i_.y = (int)b1_;                           \
    f16x4 pf0_ = __builtin_bit_cast(f16x4, p0i_);                              \
    f16x4 pf1_ = __builtin_bit_cast(f16x4, p1i_);                              \
    _Pragma("unroll")                                                          \
    for (int dt = 0; dt < 4; ++dt) {                                           \
      int2 vlo_; vlo_.x = VB_[dt].x; vlo_.y = VB_[dt].y;                       \
      int2 vhi_; vhi_.x = VB_[dt].z; vhi_.y = VB_[dt].w;                       \
      f16x4 v0_ = __builtin_bit_cast(f16x4, vlo_);                             \
      f16x4 v1_ = __builtin_bit_cast(f16x4, vhi_);                             \
      oacc[dt] = __builtin_amdgcn_mfma_f32_32x32x8f16(v0_, pf0_, oacc[dt], 0, 0, 0); \
      oacc[dt] = __builtin_amdgcn_mfma_f32_32x32x8f16(v1_, pf1_, oacc[dt], 0, 0, 0); \
    }                                                                          \
  } while (0)

#define VISSUE(ARR_, T_)                                                       \
  do {                                                                         \
    _Pragma("unroll")                                                          \
    for (int dt = 0; dt < 4; ++dt)                                             \
      ARR_[dt] = vb[vbase + (T_) * 256 + dt * 32];                             \
  } while (0)

  for (int it = 0; it < NITER; ++it) {
    const int cur = it & 1;
    // implicit vmcnt(0)+lgkmcnt(0) drain before s_barrier: buf[cur] DMA done
    __syncthreads();

    // issue NEXT K tile's DMA into buf[cur^1]; waits at the NEXT barrier
    if (it + 1 < NITER) {
      const unsigned short* ks = kwb + (long)(it + 1) * TILE_E + woff + lane * 8;
      const int nxt = cur ^ 1;
#pragma unroll
      for (int c = 0; c < 4; ++c)
        gl_lds16(ks + c * 512, &kt_lds[nxt][woff + c * 512]);
    }

    // ---- S^T = K * Q^T (32x32x16): lane holds S[q=ml][k=kt*32+(r&3)+8(r>>2)+4hi] ----
    f32x16 sacc[2];
    sacc[0] = (f32x16)(0.f);
    sacc[1] = (f32x16)(0.f);

#pragma unroll
    for (int dc = 0; dc < 8; ++dc) {
#pragma unroll
      for (int kt = 0; kt < 2; ++kt) {
        int row = kt * 32 + ml;
        int pos = (2 * dc + hi) ^ (row & 15);
        f16x8 af = *(const f16x8*)(kt_lds[cur] + row * HD + pos * 8);
        sacc[kt] = __builtin_amdgcn_mfma_f32_32x32x16_f16(
            af, qf[dc], sacc[kt], 0, 0, 0);
      }
    }

    // issue V units for t=0,1 NOW: softmax (~500 cyc) covers the latency
    const int4* vb = vw4 + (long)it * 1024;
    int4 va_[4], vbv_[4], vc_[4], vd_[4];
    VISSUE(va_, 0);
    VISSUE(vbv_, 1);

    // ---- online softmax: one q-column per lane ----
    float x0 = fmaxf(sacc[0][0], sacc[1][0]);
    float x1 = fmaxf(sacc[0][1], sacc[1][1]);
    float x2 = fmaxf(sacc[0][2], sacc[1][2]);
    float x3 = fmaxf(sacc[0][3], sacc[1][3]);
#pragma unroll
    for (int r = 4; r < 16; r += 4) {
      x0 = fmaxf(x0, fmaxf(sacc[0][r + 0], sacc[1][r + 0]));
      x1 = fmaxf(x1, fmaxf(sacc[0][r + 1], sacc[1][r + 1]));
      x2 = fmaxf(x2, fmaxf(sacc[0][r + 2], sacc[1][r + 2]));
      x3 = fmaxf(x3, fmaxf(sacc[0][r + 3], sacc[1][r + 3]));
    }
    float mx = fmaxf(fmaxf(x0, x1), fmaxf(x2, x3));
    mx = fmaxf(mx, __shfl_xor(mx, 32, 64));  // proven cross-half reduce

    // defer-max: skip rescale when running max unchanged (alpha would be exactly 1)
    if (__any(mx > mst)) {
      float mnew = fmaxf(mst, mx);
      float alpha = __builtin_amdgcn_exp2f(K1 * (mst - mnew));
      mst = mnew;
      lst *= alpha;
#pragma unroll
      for (int dt = 0; dt < 4; ++dt)
        oacc[dt] *= alpha;
    }

    const float nm = -K1 * mst;
    float p0 = 0.f, p1 = 0.f, p2 = 0.f, p3 = 0.f;
#pragma unroll
    for (int kt = 0; kt < 2; ++kt) {
#pragma unroll
      for (int r = 0; r < 16; r += 4) {
        float e0 = __builtin_amdgcn_exp2f(fmaf(sacc[kt][r + 0], K1, nm));
        float e1 = __builtin_amdgcn_exp2f(fmaf(sacc[kt][r + 1], K1, nm));
        float e2 = __builtin_amdgcn_exp2f(fmaf(sacc[kt][r + 2], K1, nm));
        float e3 = __builtin_amdgcn_exp2f(fmaf(sacc[kt][r + 3], K1, nm));
        sacc[kt][r + 0] = e0; p0 += e0;
        sacc[kt][r + 1] = e1; p1 += e1;
        sacc[kt][r + 2] = e2; p2 += e2;
        sacc[kt][r + 3] = e3; p3 += e3;
      }
    }
    lst += (p0 + p1) + (p2 + p3);  // half-lane-partial l (reduced at epilogue)

    // ---- O^T += V^T * P^T (32x32x8), lane-local P, V prefetched 2 steps ahead ----
    VISSUE(vc_, 2);
    PVSTEP(0, va_);
    VISSUE(vd_, 3);
    PVSTEP(1, vbv_);
    PVSTEP(2, vc_);
    PVSTEP(3, vd_);
  }

#undef PVSTEP
#undef VISSUE

  // ---- epilogue: finish l across half-waves, normalize, float4 stores ----
  float lf = lst + __shfl_xor(lst, 32, 64);
  float linv = 1.0f / lf;
#pragma unroll
  for (int dt = 0; dt < 4; ++dt) {
#pragma unroll
    for (int t = 0; t < 4; ++t) {
      f32x4 ov;
      ov[0] = oacc[dt][4 * t + 0] * linv;
      ov[1] = oacc[dt][4 * t + 1] * linv;
      ov[2] = oacc[dt][4 * t + 2] * linv;
      ov[3] = oacc[dt][4 * t + 3] * linv;
      *(f32x4*)(Ow + ml * HD + dt * 32 + 8 * t + 4 * hi) = ov;
    }
  }
}

extern "C" void kernel_launch(void* const* d_in, const int* in_sizes, int n_in,
                              void* d_out, int out_size, void* d_ws, size_t ws_size,
                              hipStream_t stream) {
  const float* q = (const float*)d_in[0];
  const float* k = (const float*)d_in[1];
  const float* v = (const float*)d_in[2];
  float* o = (float*)d_out;
  // workspace: Kw (8.39 MB swizzled tiles) + Vw (8.39 MB paired-frag linear)
  unsigned short* Kw = (unsigned short*)d_ws;
  unsigned short* Vw = Kw + (long)NKVH * NITER * TILE_E;
  cvt_kv<<<dim3(NKVH * NITER), dim3(256), 0, stream>>>(k, v, Kw, Vw);
  fa_gqa_kernel<<<dim3(1024), dim3(256), 0, stream>>>(q, Kw, Vw, o);
}

// Round 13
// 304.346 us; speedup vs baseline: 1.1262x; 1.1262x over previous
//
#include <hip/hip_runtime.h>

#define SEQ    2048
#define HD     128
#define BN     64
#define NITER  (SEQ / BN)
#define NKVH   16
#define TILE_E 8192   // f16 elements per 64x128 tile (16 KB)

typedef __fp16 f16x8  __attribute__((ext_vector_type(8)));
typedef float  f32x4  __attribute__((ext_vector_type(4)));
typedef float  f32x16 __attribute__((ext_vector_type(16)));

// pack two fp32 -> one uint of two f16 (RTZ)
__device__ __forceinline__ unsigned pkh(float a, float b) {
  auto h = __builtin_amdgcn_cvt_pkrtz(a, b);
  return __builtin_bit_cast(unsigned, h);
}

// direct HBM/L2 -> LDS DMA, 16 B per lane; lds dest wave-uniform base + lane*16
__device__ __forceinline__ void gl_lds16(const unsigned short* g, unsigned short* l) {
  __builtin_amdgcn_global_load_lds(
      (const __attribute__((address_space(1))) void*)g,
      (__attribute__((address_space(3))) void*)l, 16, 0, 0);
}

// ---------------------------------------------------------------------------
// Pass 1: K,V fp32 -> f16 tiles in workspace, PRE-SWIZZLED in the exact LDS
// byte layout of the main kernel (so main-kernel staging is a linear copy).
// K tile [64 k][128 d]: 16B chunk j at pos j ^ (row&15).
// V^T tile [128 d][64 k]: 16B chunk c8 at pos c8 ^ (((d>>3)^d)&7).
// Tiles are contiguous: head hh, tile t -> element offset (hh*32+t)*8192.
// ---------------------------------------------------------------------------
__global__ __launch_bounds__(256)
void cvt_kv(const float* __restrict__ K, const float* __restrict__ V,
            unsigned short* __restrict__ Kw, unsigned short* __restrict__ Vw)
{
  __shared__ unsigned short kt[TILE_E];
  __shared__ unsigned short vt[TILE_E];
  const int tid = threadIdx.x;
  const int T   = blockIdx.x;               // 0..511 = hh*32 + t
  const long base = (long)T * TILE_E;       // fp32 element offset (same count)

  // K staging (R0-verified arithmetic)
  const int krow = tid >> 2, kq4 = tid & 3;
  const float* kp = K + base + (long)krow * HD + kq4 * 32;
#pragma unroll
  for (int jj = 0; jj < 4; ++jj) {
    float4 e = ((const float4*)kp)[2 * jj];
    float4 o = ((const float4*)kp)[2 * jj + 1];
    int4 ksj;
    ksj.x = (int)pkh(e.x, e.y);
    ksj.y = (int)pkh(e.z, e.w);
    ksj.z = (int)pkh(o.x, o.y);
    ksj.w = (int)pkh(o.z, o.w);
    int j = kq4 * 4 + jj;
    int pos = j ^ (krow & 15);
    *(int4*)(kt + krow * HD + pos * 8) = ksj;
  }
  // V^T staging (R0-verified arithmetic)
  const int kq = tid >> 4, dc8 = tid & 15;
  const float* vp = V + base + (long)(4 * kq) * HD + dc8 * 8;
  float4 vr[4][2];
#pragma unroll
  for (int r = 0; r < 4; ++r) {
    vr[r][0] = ((const float4*)(vp + r * HD))[0];
    vr[r][1] = ((const float4*)(vp + r * HD))[1];
  }
#pragma unroll
  for (int jd = 0; jd < 8; ++jd) {
    const int hsel = jd >> 2, e = jd & 3;
    uint2 v2;
    v2.x = pkh(((const float*)&vr[0][hsel])[e], ((const float*)&vr[1][hsel])[e]);
    v2.y = pkh(((const float*)&vr[2][hsel])[e], ((const float*)&vr[3][hsel])[e]);
    int d = dc8 * 8 + jd;
    int sw3 = ((d >> 3) ^ d) & 7;
    int pos = (kq >> 1) ^ sw3;
    *(uint2*)(vt + d * 64 + pos * 8 + (kq & 1) * 4) = v2;
  }
  __syncthreads();
  // linear dump LDS -> workspace (coalesced dwordx4)
  int4* kd = (int4*)(Kw + (long)T * TILE_E);
  int4* vd = (int4*)(Vw + (long)T * TILE_E);
  const int4* ksrc = (const int4*)kt;
  const int4* vsrc = (const int4*)vt;
#pragma unroll
  for (int i = 0; i < 4; ++i) {
    kd[i * 256 + tid] = ksrc[i * 256 + tid];
    vd[i * 256 + tid] = vsrc[i * 256 + tid];
  }
}

// ---------------------------------------------------------------------------
// Pass 2: attention (R7 skeleton, ILP-reordered):
//  - K,V: global_load_lds DMA of pre-swizzled tiles, LDS double-buffered,
//    one barrier/iter, zero staging registers, zero bank conflicts.
//  - kt-OUTER QK^T: sacc[0]'s chain completes halfway -> its max-tree
//    schedules under sacc[1]'s MFMA chain (dependent-acc MFMA chains issue
//    at full rate, so kt-outer costs nothing).
//  - exp/PV split by kt: exp(kt0) -> PV st0,st1 (consume only kt0; their
//    ds_bpermute + ds_read latency overlaps exp(kt1)) -> exp(kt1) -> st2,st3.
// ---------------------------------------------------------------------------
__global__ __launch_bounds__(256, 2)
void fa_gqa_kernel(const float* __restrict__ Q,
                   const unsigned short* __restrict__ Kw,
                   const unsigned short* __restrict__ Vw,
                   float* __restrict__ O)
{
  __shared__ unsigned short kt_lds[2][TILE_E];
  __shared__ unsigned short vt_lds[2][TILE_E];

  const int tid  = threadIdx.x;
  const int lane = tid & 63;
  const int w    = tid >> 6;
  const int ml   = lane & 31;   // 32x32 MFMA row/col lane index
  const int hi   = lane >> 5;   // half-wave select
  const bool hib = (hi != 0);

  // XCD-clustered virtual block mapping (K/V L2 locality)
  const int F     = blockIdx.x;        // 0..1023
  const int xcd   = F & 7;
  const int s     = F >> 3;
  const int bh    = xcd * 8 + (s >> 4);
  const int qtile = s & 15;

  const int b = bh >> 5;
  const int h = bh & 31;
  const long qrow0 = (long)bh * SEQ + qtile * 128 + w * 32;
  const float* Qw = Q + qrow0 * HD;
  float*       Ow = O + qrow0 * HD;
  const int kvh = b * 8 + (h >> 2);

  // Q fragments (B-operand of 32x32x16: lane holds Q[q=w*32+ml][d=dc*16+hi*8+j])
  f16x8 qf[8];
#pragma unroll
  for (int dc = 0; dc < 8; ++dc) {
    const float4* qp = (const float4*)(Qw + ml * HD + dc * 16 + hi * 8);
    float4 a = qp[0], bq = qp[1];
    int4 t;
    t.x = (int)pkh(a.x, a.y);
    t.y = (int)pkh(a.z, a.w);
    t.z = (int)pkh(bq.x, bq.y);
    t.w = (int)pkh(bq.z, bq.w);
    qf[dc] = __builtin_bit_cast(f16x8, t);
  }

  // O^T accumulators: 4 d-tiles of 32x32; lane holds O[q=ml][d=dt*32+(r&3)+8(r>>2)+4hi]
  f32x16 oacc[4];
#pragma unroll
  for (int dt = 0; dt < 4; ++dt)
    oacc[dt] = (f32x16)(0.f);

  float mst = -1e30f;
  float lst = 0.f;

  const float K1 = 0.08838834764831845f * 1.4426950408889634f; // scale*log2(e)

  // staging: wave w copies quarter w (4 KB) of each tile; pre-swizzled source,
  // linear LDS dest (the legal global_load_lds pattern)
  const unsigned short* kwb = Kw + (long)kvh * NITER * TILE_E;
  const unsigned short* vwb = Vw + (long)kvh * NITER * TILE_E;
  const int woff = w * 2048;  // elements = 4 KB

  // prologue: issue tile 0 into buf 0
  {
    const unsigned short* ks = kwb + woff + lane * 8;
    const unsigned short* vs = vwb + woff + lane * 8;
#pragma unroll
    for (int c = 0; c < 4; ++c) {
      gl_lds16(ks + c * 512, &kt_lds[0][woff + c * 512]);
      gl_lds16(vs + c * 512, &vt_lds[0][woff + c * 512]);
    }
  }

// one PV k-step of 16 (32x32x16), B-frag assembled via proven shfl exchange
#define PVSTEP(ST_)                                                            \
  do {                                                                         \
    const int kt_ = (ST_) >> 1;                                                \
    const int R_  = 8 * ((ST_) & 1);                                           \
    unsigned pA0 = pkh(sacc[kt_][R_ + 0], sacc[kt_][R_ + 1]);                  \
    unsigned pA1 = pkh(sacc[kt_][R_ + 2], sacc[kt_][R_ + 3]);                  \
    unsigned pB0 = pkh(sacc[kt_][R_ + 4], sacc[kt_][R_ + 5]);                  \
    unsigned pB1 = pkh(sacc[kt_][R_ + 6], sacc[kt_][R_ + 7]);                  \
    unsigned s0 = hib ? pA0 : pB0;                                             \
    unsigned s1 = hib ? pA1 : pB1;                                             \
    unsigned r0 = (unsigned)__shfl_xor((int)s0, 32, 64);                       \
    unsigned r1 = (unsigned)__shfl_xor((int)s1, 32, 64);                       \
    int4 bf;                                                                   \
    bf.x = (int)(hib ? r0 : pA0);                                              \
    bf.y = (int)(hib ? r1 : pA1);                                              \
    bf.z = (int)(hib ? pB0 : r0);                                              \
    bf.w = (int)(hib ? pB1 : r1);                                              \
    f16x8 pfrag = __builtin_bit_cast(f16x8, bf);                               \
    _Pragma("unroll")                                                          \
    for (int dt = 0; dt < 4; ++dt) {                                           \
      int d = dt * 32 + ml;                                                    \
      int pos = (2 * (ST_) + hi) ^ (((d >> 3) ^ d) & 7);                       \
      f16x8 vf = *(const f16x8*)(vt_lds[cur] + d * 64 + pos * 8);              \
      oacc[dt] = __builtin_amdgcn_mfma_f32_32x32x16_f16(                       \
          vf, pfrag, oacc[dt], 0, 0, 0);                                       \
    }                                                                          \
  } while (0)

// exp pass over one kt half (in-place, 4 parallel sum chains)
#define EXPPASS(KT_)                                                           \
  do {                                                                         \
    _Pragma("unroll")                                                          \
    for (int r = 0; r < 16; r += 4) {                                          \
      float e0 = __builtin_amdgcn_exp2f(fmaf(sacc[KT_][r + 0], K1, nm));       \
      float e1 = __builtin_amdgcn_exp2f(fmaf(sacc[KT_][r + 1], K1, nm));       \
      float e2 = __builtin_amdgcn_exp2f(fmaf(sacc[KT_][r + 2], K1, nm));       \
      float e3 = __builtin_amdgcn_exp2f(fmaf(sacc[KT_][r + 3], K1, nm));       \
      sacc[KT_][r + 0] = e0; p0 += e0;                                         \
      sacc[KT_][r + 1] = e1; p1 += e1;                                         \
      sacc[KT_][r + 2] = e2; p2 += e2;                                         \
      sacc[KT_][r + 3] = e3; p3 += e3;                                         \
    }                                                                          \
  } while (0)

  for (int it = 0; it < NITER; ++it) {
    const int cur = it & 1;
    // implicit vmcnt(0)+lgkmcnt(0) drain before s_barrier: buf[cur] DMA complete
    // in every wave, and all waves are done reading buf[cur^1]
    __syncthreads();

    // issue NEXT tile's DMA into buf[cur^1]; waits at the NEXT barrier,
    // i.e. the loads have the whole compute phase in flight
    if (it + 1 < NITER) {
      const unsigned short* ks = kwb + (long)(it + 1) * TILE_E + woff + lane * 8;
      const unsigned short* vs = vwb + (long)(it + 1) * TILE_E + woff + lane * 8;
      const int nxt = cur ^ 1;
#pragma unroll
      for (int c = 0; c < 4; ++c) {
        gl_lds16(ks + c * 512, &kt_lds[nxt][woff + c * 512]);
        gl_lds16(vs + c * 512, &vt_lds[nxt][woff + c * 512]);
      }
    }

    // ---- S^T = K * Q^T (32x32x16), kt-OUTER: sacc[0] chain first so its
    //      max-tree can be scheduled under sacc[1]'s chain ----
    f32x16 sacc[2];
    sacc[0] = (f32x16)(0.f);
    sacc[1] = (f32x16)(0.f);

#pragma unroll
    for (int dc = 0; dc < 8; ++dc) {
      int row = ml;
      int pos = (2 * dc + hi) ^ (row & 15);
      f16x8 af = *(const f16x8*)(kt_lds[cur] + row * HD + pos * 8);
      sacc[0] = __builtin_amdgcn_mfma_f32_32x32x16_f16(af, qf[dc], sacc[0], 0, 0, 0);
    }

    // max-tree over sacc[0] (source-placed before kt=1 chain: overlaps it)
    float x0 = sacc[0][0], x1 = sacc[0][1], x2 = sacc[0][2], x3 = sacc[0][3];
#pragma unroll
    for (int r = 4; r < 16; r += 4) {
      x0 = fmaxf(x0, sacc[0][r + 0]);
      x1 = fmaxf(x1, sacc[0][r + 1]);
      x2 = fmaxf(x2, sacc[0][r + 2]);
      x3 = fmaxf(x3, sacc[0][r + 3]);
    }

#pragma unroll
    for (int dc = 0; dc < 8; ++dc) {
      int row = 32 + ml;
      int pos = (2 * dc + hi) ^ (row & 15);
      f16x8 af = *(const f16x8*)(kt_lds[cur] + row * HD + pos * 8);
      sacc[1] = __builtin_amdgcn_mfma_f32_32x32x16_f16(af, qf[dc], sacc[1], 0, 0, 0);
    }

    // fold in sacc[1]'s max
#pragma unroll
    for (int r = 0; r < 16; r += 4) {
      x0 = fmaxf(x0, sacc[1][r + 0]);
      x1 = fmaxf(x1, sacc[1][r + 1]);
      x2 = fmaxf(x2, sacc[1][r + 2]);
      x3 = fmaxf(x3, sacc[1][r + 3]);
    }
    float mx = fmaxf(fmaxf(x0, x1), fmaxf(x2, x3));
    mx = fmaxf(mx, __shfl_xor(mx, 32, 64));  // proven cross-half reduce

    // defer-max: skip rescale when running max unchanged (alpha would be exactly 1)
    if (__any(mx > mst)) {
      float mnew = fmaxf(mst, mx);
      float alpha = __builtin_amdgcn_exp2f(K1 * (mst - mnew));
      mst = mnew;
      lst *= alpha;
#pragma unroll
      for (int dt = 0; dt < 4; ++dt)
        oacc[dt] *= alpha;
    }

    const float nm = -K1 * mst;
    float p0 = 0.f, p1 = 0.f, p2 = 0.f, p3 = 0.f;

    // exp(kt0) -> PV st0,st1 (only need kt0; their bpermute/ds_read latency
    // overlaps exp(kt1)) -> exp(kt1) -> PV st2,st3
    EXPPASS(0);
    PVSTEP(0);
    EXPPASS(1);
    PVSTEP(1);
    PVSTEP(2);
    PVSTEP(3);

    lst += (p0 + p1) + (p2 + p3);  // half-lane-partial l (reduced at epilogue)
  }

#undef PVSTEP
#undef EXPPASS

  // ---- epilogue: finish l across half-waves, normalize, float4 stores ----
  float lf = lst + __shfl_xor(lst, 32, 64);
  float linv = 1.0f / lf;
#pragma unroll
  for (int dt = 0; dt < 4; ++dt) {
#pragma unroll
    for (int t = 0; t < 4; ++t) {
      f32x4 ov;
      ov[0] = oacc[dt][4 * t + 0] * linv;
      ov[1] = oacc[dt][4 * t + 1] * linv;
      ov[2] = oacc[dt][4 * t + 2] * linv;
      ov[3] = oacc[dt][4 * t + 3] * linv;
      *(f32x4*)(Ow + ml * HD + dt * 32 + 8 * t + 4 * hi) = ov;
    }
  }
}

extern "C" void kernel_launch(void* const* d_in, const int* in_sizes, int n_in,
                              void* d_out, int out_size, void* d_ws, size_t ws_size,
                              hipStream_t stream) {
  const float* q = (const float*)d_in[0];
  const float* k = (const float*)d_in[1];
  const float* v = (const float*)d_in[2];
  float* o = (float*)d_out;
  // workspace: Kw (8.39 MB) + Vw (8.39 MB) f16 pre-swizzled tiles
  unsigned short* Kw = (unsigned short*)d_ws;
  unsigned short* Vw = Kw + (long)NKVH * NITER * TILE_E;
  cvt_kv<<<dim3(NKVH * NITER), dim3(256), 0, stream>>>(k, v, Kw, Vw);
  fa_gqa_kernel<<<dim3(1024), dim3(256), 0, stream>>>(q, Kw, Vw, o);
}